// Round 1
// baseline (168.911 us; speedup 1.0000x reference)
//
#include <hip/hip_runtime.h>
#include <stdint.h>

#define HW 512
#define WPR 8                    // uint64 words per row (512/64)
#define IMG_WORDS (HW * WPR)     // 4096 words per image
#define NIMG 8
#define PIX_PER_IMG (HW * HW)    // 262144
#define TOTAL_PIX (NIMG * PIX_PER_IMG)  // 2097152
#define MASK_WORDS (TOTAL_PIX / 64)     // 32768 words per mask set

// ---------------------------------------------------------------------------
// Pack: binarize pred/target into bit masks (64 px per uint64 via ballot).
// Also zeroes the accumulators (block 0) -- d_ws is poisoned before each call.
// ---------------------------------------------------------------------------
__global__ void pack_kernel(const float* __restrict__ pred,
                            const float* __restrict__ target,
                            uint64_t* __restrict__ gt_bin,
                            uint64_t* __restrict__ pr_bin,
                            float* __restrict__ sums, int* __restrict__ cnts) {
    int idx = blockIdx.x * 256 + threadIdx.x;
    if (blockIdx.x == 0 && threadIdx.x < NIMG) {
        sums[threadIdx.x] = 0.0f;
        cnts[threadIdx.x] = 0;
    }
    float p = pred[idx];
    float t = target[idx];
    uint64_t bp = __ballot(p > 0.5f);   // FILTER_P
    uint64_t bt = __ballot(t > 0.5f);
    if ((threadIdx.x & 63) == 0) {
        int w = idx >> 6;
        pr_bin[w] = bp;
        gt_bin[w] = bt;
    }
}

// ---------------------------------------------------------------------------
// Zhang-Suen sub-step for one row (8 words), bit-parallel.
// LDS layout: lds[wx * 512 + row]  (column-of-words major -> conflict-free
// ds_read_b64 across lanes, stride 8B).
// ---------------------------------------------------------------------------
template <int STEP>
__device__ inline void zs_substep(uint64_t* lds, int r, int* s_changed) {
    uint64_t U[WPR], C[WPR], D[WPR], NEW[WPR];
#pragma unroll
    for (int w = 0; w < WPR; ++w) {
        C[w] = lds[w * HW + r];
        U[w] = (r > 0)      ? lds[w * HW + r - 1] : 0ull;
        D[w] = (r < HW - 1) ? lds[w * HW + r + 1] : 0ull;
    }
    uint64_t changed = 0;
#pragma unroll
    for (int w = 0; w < WPR; ++w) {
        uint64_t Cl = (w > 0) ? C[w - 1] : 0ull, Cr = (w < 7) ? C[w + 1] : 0ull;
        uint64_t Ul = (w > 0) ? U[w - 1] : 0ull, Ur = (w < 7) ? U[w + 1] : 0ull;
        uint64_t Dl = (w > 0) ? D[w - 1] : 0ull, Dr = (w < 7) ? D[w + 1] : 0ull;
        // bit i of word = pixel x = w*64 + i; east neighbor = bit i+1
        uint64_t P2 = U[w];                       // N
        uint64_t P6 = D[w];                       // S
        uint64_t P4 = (C[w] >> 1) | (Cr << 63);   // E
        uint64_t P8 = (C[w] << 1) | (Cl >> 63);   // W
        uint64_t P3 = (U[w] >> 1) | (Ur << 63);   // NE
        uint64_t P9 = (U[w] << 1) | (Ul >> 63);   // NW
        uint64_t P5 = (D[w] >> 1) | (Dr << 63);   // SE
        uint64_t P7 = (D[w] << 1) | (Dl >> 63);   // SW

        // ---- B = popcount of 8 neighbors, bit-sliced CSA ----
        uint64_t s1 = P2 ^ P3, sum1 = s1 ^ P4, car1 = (P2 & P3) | (P4 & s1);
        uint64_t s2 = P5 ^ P6, sum2 = s2 ^ P7, car2 = (P5 & P6) | (P7 & s2);
        uint64_t s3 = sum1 ^ sum2, sum3 = s3 ^ P8, car3 = (sum1 & sum2) | (P8 & s3);
        uint64_t b0 = sum3 ^ P9, car4 = sum3 & P9;
        uint64_t s5 = car1 ^ car2, sum5 = s5 ^ car3, car5 = (car1 & car2) | (car3 & s5);
        uint64_t b1 = sum5 ^ car4, car6 = sum5 & car4;
        uint64_t b2 = car5 ^ car6, b3 = car5 & car6;
        uint64_t ge2 = b1 | b2 | b3;                    // B >= 2
        uint64_t le6 = ~(b3 | (b0 & b1 & b2));          // B <= 6 (not 7, not 8)
        uint64_t condB = ge2 & le6;

        // ---- A == 1: exactly one 0->1 transition in P2..P9,P2 ----
        uint64_t t0 = ~P2 & P3, t1 = ~P3 & P4, t2 = ~P4 & P5, t3 = ~P5 & P6;
        uint64_t t4 = ~P6 & P7, t5 = ~P7 & P8, t6 = ~P8 & P9, t7 = ~P9 & P2;
        uint64_t a01 = t0 | t1, a23 = t2 | t3, a45 = t4 | t5, a67 = t6 | t7;
        uint64_t m2 = (t0 & t1) | (t2 & t3) | (t4 & t5) | (t6 & t7);
        uint64_t a0123 = a01 | a23, a4567 = a45 | a67;
        m2 |= (a01 & a23) | (a45 & a67);
        m2 |= a0123 & a4567;
        uint64_t condA = (a0123 | a4567) & ~m2;

        uint64_t c1, c2;
        if (STEP == 0) {
            uint64_t q = P4 & P6;
            c1 = ~(q & P2);   // P2*P4*P6 == 0
            c2 = ~(q & P8);   // P4*P6*P8 == 0
        } else {
            uint64_t q = P2 & P8;
            c1 = ~(q & P4);   // P2*P4*P8 == 0
            c2 = ~(q & P6);   // P2*P6*P8 == 0
        }
        uint64_t rem = C[w] & condB & condA & c1 & c2;
        NEW[w] = C[w] & ~rem;
        changed |= rem;
    }
    __syncthreads();   // all reads of old image done
#pragma unroll
    for (int w = 0; w < WPR; ++w) lds[w * HW + r] = NEW[w];
    if (changed) *s_changed = 1;
    __syncthreads();   // writes + flag visible
}

// ---------------------------------------------------------------------------
// Skeletonize: one block per (mask,image) task. 16 blocks x 512 threads.
// Iterate ZS (substep0; substep1) until no change (cap 300 = safe for any
// 512x512 input; thinning is monotone so extra iterations are idempotent).
// ---------------------------------------------------------------------------
__global__ __launch_bounds__(512) void skel_kernel(const uint64_t* __restrict__ bin_base,
                                                   uint64_t* __restrict__ sk_base) {
    __shared__ uint64_t lds[WPR * HW];   // 32 KiB, [wx][row]
    __shared__ int s_changed;
    const int tid = threadIdx.x;
    const uint64_t* src = bin_base + (size_t)blockIdx.x * IMG_WORDS;
    uint64_t* dst = sk_base + (size_t)blockIdx.x * IMG_WORDS;

#pragma unroll
    for (int k = 0; k < 8; ++k) {
        int g = tid + k * 512;                 // coalesced global read
        lds[(g & 7) * HW + (g >> 3)] = src[g]; // transpose into [wx][row]
    }
    __syncthreads();

    const int r = tid;
    for (int it = 0; it < 300; ++it) {
        if (tid == 0) s_changed = 0;
        __syncthreads();
        zs_substep<0>(lds, r, &s_changed);
        zs_substep<1>(lds, r, &s_changed);
        int ch = s_changed;
        __syncthreads();
        if (!ch) break;
    }

#pragma unroll
    for (int k = 0; k < 8; ++k) {
        int g = tid + k * 512;
        dst[g] = lds[(g & 7) * HW + (g >> 3)];
    }
}

// ---------------------------------------------------------------------------
// BCE over selected pixels; per-image sum + count via block reduce + atomics.
// Each block handles 1024 consecutive pixels (always within one image).
// ---------------------------------------------------------------------------
__global__ void bce_kernel(const float* __restrict__ pred,
                           const float* __restrict__ target,
                           const uint64_t* __restrict__ gt_bin,
                           const uint64_t* __restrict__ pr_bin,
                           const uint64_t* __restrict__ gt_sk,
                           const uint64_t* __restrict__ pr_sk,
                           float* __restrict__ sums, int* __restrict__ cnts) {
    int base = blockIdx.x * 1024;
    float lsum = 0.0f;
    int lcnt = 0;
#pragma unroll
    for (int k = 0; k < 4; ++k) {
        int pix = base + k * 256 + threadIdx.x;
        int w = pix >> 6;
        int bit = pix & 63;
        uint64_t sel = (gt_sk[w] & ~pr_bin[w]) | (pr_sk[w] & ~gt_bin[w]);
        if ((sel >> bit) & 1ull) {
            float p = pred[pix], t = target[pix];
            float lp = fmaxf(logf(p), -100.0f);
            float l1 = fmaxf(log1pf(-p), -100.0f);
            lsum += -(t * lp + (1.0f - t) * l1);
            lcnt += 1;
        }
    }
    // wave (64) reduce
#pragma unroll
    for (int off = 32; off > 0; off >>= 1) {
        lsum += __shfl_down(lsum, off, 64);
        lcnt += __shfl_down(lcnt, off, 64);
    }
    __shared__ float sred[4];
    __shared__ int cred[4];
    int wave = threadIdx.x >> 6, lane = threadIdx.x & 63;
    if (lane == 0) { sred[wave] = lsum; cred[wave] = lcnt; }
    __syncthreads();
    if (threadIdx.x == 0) {
        float s = sred[0] + sred[1] + sred[2] + sred[3];
        int c = cred[0] + cred[1] + cred[2] + cred[3];
        int img = base >> 18;   // 262144 px per image
        atomicAdd(&sums[img], s);
        atomicAdd(&cnts[img], c);
    }
}

__global__ void final_kernel(const float* __restrict__ sums,
                             const int* __restrict__ cnts,
                             float* __restrict__ out) {
    if (threadIdx.x == 0) {
        float tot = 0.0f;
#pragma unroll
        for (int i = 0; i < NIMG; ++i) {
            float c = (float)cnts[i];
            tot += (c > 0.0f) ? (sums[i] / c) : 0.0f;
        }
        out[0] = tot * (1.0f / NIMG);
    }
}

// ---------------------------------------------------------------------------
extern "C" void kernel_launch(void* const* d_in, const int* in_sizes, int n_in,
                              void* d_out, int out_size, void* d_ws, size_t ws_size,
                              hipStream_t stream) {
    const float* pred = (const float*)d_in[0];
    const float* target = (const float*)d_in[1];
    uint64_t* ws = (uint64_t*)d_ws;
    // ws layout (uint64 units):
    uint64_t* gt_bin = ws;                      // [0, 32768)
    uint64_t* pr_bin = ws + MASK_WORDS;         // [32768, 65536)
    uint64_t* sk     = ws + 2 * MASK_WORDS;     // gt_sk then pr_sk, 65536 words
    uint64_t* gt_sk  = sk;
    uint64_t* pr_sk  = sk + MASK_WORDS;
    float* sums = (float*)(ws + 4 * MASK_WORDS);
    int* cnts   = (int*)(sums + NIMG);

    pack_kernel<<<TOTAL_PIX / 256, 256, 0, stream>>>(pred, target, gt_bin, pr_bin, sums, cnts);
    // bin region (gt then pr) is 16 contiguous images; same for sk region.
    skel_kernel<<<16, 512, 0, stream>>>(gt_bin, gt_sk);
    bce_kernel<<<TOTAL_PIX / 1024, 256, 0, stream>>>(pred, target, gt_bin, pr_bin, gt_sk, pr_sk, sums, cnts);
    final_kernel<<<1, 64, 0, stream>>>(sums, cnts, (float*)d_out);
}

// Round 2
// 146.796 us; speedup vs baseline: 1.1506x; 1.1506x over previous
//
#include <hip/hip_runtime.h>
#include <stdint.h>

#define HW 512
#define WPR 8                    // uint64 words per row (512/64)
#define IMG_WORDS (HW * WPR)     // 4096 words per image
#define NIMG 8
#define PIX_PER_IMG (HW * HW)    // 262144
#define TOTAL_PIX (NIMG * PIX_PER_IMG)  // 2097152
#define MASK_WORDS (TOTAL_PIX / 64)     // 32768 words per mask set

// ---------------------------------------------------------------------------
// Pack: binarize pred/target into bit masks (64 px per uint64 via ballot).
// Also zeroes the accumulators (block 0) -- d_ws is poisoned before each call.
// ---------------------------------------------------------------------------
__global__ void pack_kernel(const float* __restrict__ pred,
                            const float* __restrict__ target,
                            uint64_t* __restrict__ gt_bin,
                            uint64_t* __restrict__ pr_bin,
                            float* __restrict__ sums, int* __restrict__ cnts) {
    int idx = blockIdx.x * 256 + threadIdx.x;
    if (blockIdx.x == 0 && threadIdx.x < NIMG) {
        sums[threadIdx.x] = 0.0f;
        cnts[threadIdx.x] = 0;
    }
    float p = pred[idx];
    float t = target[idx];
    uint64_t bp = __ballot(p > 0.5f);   // FILTER_P
    uint64_t bt = __ballot(t > 0.5f);
    if ((threadIdx.x & 63) == 0) {
        int w = idx >> 6;
        pr_bin[w] = bp;
        gt_bin[w] = bt;
    }
}

// ---------------------------------------------------------------------------
// Zhang-Suen bitwise compute for one row (8 words). C/U/D in registers.
// Returns "changed" bits; fills NEW.
// ---------------------------------------------------------------------------
template <int STEP>
__device__ __forceinline__ uint64_t zs_compute(const uint64_t (&C)[WPR],
                                               const uint64_t (&U)[WPR],
                                               const uint64_t (&D)[WPR],
                                               uint64_t (&NEW)[WPR]) {
    uint64_t changed = 0;
#pragma unroll
    for (int w = 0; w < WPR; ++w) {
        uint64_t Cl = (w > 0) ? C[w - 1] : 0ull, Cr = (w < 7) ? C[w + 1] : 0ull;
        uint64_t Ul = (w > 0) ? U[w - 1] : 0ull, Ur = (w < 7) ? U[w + 1] : 0ull;
        uint64_t Dl = (w > 0) ? D[w - 1] : 0ull, Dr = (w < 7) ? D[w + 1] : 0ull;
        // bit i of word = pixel x = w*64 + i; east neighbor = bit i+1
        uint64_t P2 = U[w];                       // N
        uint64_t P6 = D[w];                       // S
        uint64_t P4 = (C[w] >> 1) | (Cr << 63);   // E
        uint64_t P8 = (C[w] << 1) | (Cl >> 63);   // W
        uint64_t P3 = (U[w] >> 1) | (Ur << 63);   // NE
        uint64_t P9 = (U[w] << 1) | (Ul >> 63);   // NW
        uint64_t P5 = (D[w] >> 1) | (Dr << 63);   // SE
        uint64_t P7 = (D[w] << 1) | (Dl >> 63);   // SW

        // ---- B = popcount of 8 neighbors, bit-sliced CSA ----
        uint64_t s1 = P2 ^ P3, sum1 = s1 ^ P4, car1 = (P2 & P3) | (P4 & s1);
        uint64_t s2 = P5 ^ P6, sum2 = s2 ^ P7, car2 = (P5 & P6) | (P7 & s2);
        uint64_t s3 = sum1 ^ sum2, sum3 = s3 ^ P8, car3 = (sum1 & sum2) | (P8 & s3);
        uint64_t b0 = sum3 ^ P9, car4 = sum3 & P9;
        uint64_t s5 = car1 ^ car2, sum5 = s5 ^ car3, car5 = (car1 & car2) | (car3 & s5);
        uint64_t b1 = sum5 ^ car4, car6 = sum5 & car4;
        uint64_t b2 = car5 ^ car6, b3 = car5 & car6;
        uint64_t ge2 = b1 | b2 | b3;                    // B >= 2
        uint64_t le6 = ~(b3 | (b0 & b1 & b2));          // B <= 6 (not 7, not 8)
        uint64_t condB = ge2 & le6;

        // ---- A == 1: exactly one 0->1 transition in P2..P9,P2 ----
        uint64_t t0 = ~P2 & P3, t1 = ~P3 & P4, t2 = ~P4 & P5, t3 = ~P5 & P6;
        uint64_t t4 = ~P6 & P7, t5 = ~P7 & P8, t6 = ~P8 & P9, t7 = ~P9 & P2;
        uint64_t a01 = t0 | t1, a23 = t2 | t3, a45 = t4 | t5, a67 = t6 | t7;
        uint64_t m2 = (t0 & t1) | (t2 & t3) | (t4 & t5) | (t6 & t7);
        uint64_t a0123 = a01 | a23, a4567 = a45 | a67;
        m2 |= (a01 & a23) | (a45 & a67);
        m2 |= a0123 & a4567;
        uint64_t condA = (a0123 | a4567) & ~m2;

        uint64_t c1, c2;
        if (STEP == 0) {
            uint64_t q = P4 & P6;
            c1 = ~(q & P2);   // P2*P4*P6 == 0
            c2 = ~(q & P8);   // P4*P6*P8 == 0
        } else {
            uint64_t q = P2 & P8;
            c1 = ~(q & P4);   // P2*P4*P8 == 0
            c2 = ~(q & P6);   // P2*P6*P8 == 0
        }
        uint64_t rem = C[w] & condB & condA & c1 & c2;
        NEW[w] = C[w] & ~rem;
        changed |= rem;
    }
    return changed;
}

// One ZS sub-step with ping-pong state buffers (sr -> sw) and ping-pong
// dirty arrays (cr -> cw). Row r recomputes iff any change in rows r-1..r+1
// during the last two sub-steps (sound: same parity on an unchanged
// neighborhood reproduces its previous no-change result). Skipped rows do
// not write sw: staleness is safe because need==0 implies the row was
// unchanged in the last two sub-steps, so both buffers hold its value.
template <int STEP>
__device__ __forceinline__ void zs_pass(uint64_t (&C)[WPR],
                                        uint64_t* __restrict__ sr, uint64_t* __restrict__ sw,
                                        uint32_t* __restrict__ cr, uint32_t* __restrict__ cw,
                                        int r, int* flag) {
    uint32_t myc = cr[r + 1];
    uint32_t nd = (cr[r] | myc | cr[r + 2]) & 3u;
    uint64_t changed = 0;
    if (nd) {
        uint64_t U[WPR], D[WPR], NEW[WPR];
#pragma unroll
        for (int w = 0; w < WPR; ++w) {
            U[w] = (r > 0)      ? sr[w * HW + r - 1] : 0ull;
            D[w] = (r < HW - 1) ? sr[w * HW + r + 1] : 0ull;
        }
        changed = zs_compute<STEP>(C, U, D, NEW);
#pragma unroll
        for (int w = 0; w < WPR; ++w) { sw[w * HW + r] = NEW[w]; C[w] = NEW[w]; }
        if (changed) *flag = 1;
    }
    cw[r + 1] = ((myc << 1) & 2u) | (changed ? 1u : 0u);
    __syncthreads();
}

// ---------------------------------------------------------------------------
// Skeletonize: one block per (mask,image) task. 16 blocks x 512 threads.
// Thread = row (kept in registers). State ping-pongs between two LDS buffers
// (substep0: buf0->buf1, substep1: buf1->buf0), 1 barrier per substep.
// Convergence flag rotates over 3 slots so reset never races reads.
// ---------------------------------------------------------------------------
__global__ __launch_bounds__(512) void skel_kernel(const uint64_t* __restrict__ bin_base,
                                                   uint64_t* __restrict__ sk_base) {
    __shared__ uint64_t sbuf[2][WPR * HW];   // 64 KiB
    __shared__ uint32_t chg[2][HW + 2];      // dirty bits: bit0=last substep, bit1=prev
    __shared__ int s_flag[3];
    const int tid = threadIdx.x;
    const uint64_t* src = bin_base + (size_t)blockIdx.x * IMG_WORDS;
    uint64_t* dst = sk_base + (size_t)blockIdx.x * IMG_WORDS;

#pragma unroll
    for (int k = 0; k < 8; ++k) {
        int g = tid + k * 512;                     // coalesced global read
        sbuf[0][(g & 7) * HW + (g >> 3)] = src[g]; // transpose into [wx][row]
    }
    chg[0][tid + 1] = 3u;       // rows 0..511 -> indices 1..512
    chg[1][tid + 1] = 0u;
    if (tid < 2) { chg[0][tid * (HW + 1)] = 0u; chg[1][tid * (HW + 1)] = 0u; } // idx 0 and 513
    if (tid == 0) { s_flag[0] = 0; s_flag[1] = 0; s_flag[2] = 0; }
    __syncthreads();

    const int r = tid;
    uint64_t C[WPR];
#pragma unroll
    for (int w = 0; w < WPR; ++w) C[w] = sbuf[0][w * HW + r];

    for (int it = 0; it < 300; ++it) {
        if (tid == 0) s_flag[(it + 1) % 3] = 0;   // reset flag for NEXT iteration
        int* flag = &s_flag[it % 3];
        // substep 0: buf0 -> buf1, chg0 -> chg1
        zs_pass<0>(C, sbuf[0], sbuf[1], chg[0], chg[1], r, flag);
        // substep 1: buf1 -> buf0, chg1 -> chg0
        zs_pass<1>(C, sbuf[1], sbuf[0], chg[1], chg[0], r, flag);
        int ch = *flag;           // after barrier inside zs_pass<1>
        if (!ch) break;           // uniform across block
    }

    // C registers hold the converged row; store coalesced (lane r -> 64B chunk)
#pragma unroll
    for (int w = 0; w < WPR; ++w) dst[r * WPR + w] = C[w];
}

// ---------------------------------------------------------------------------
// BCE: branchless streaming. 8 px/thread via 2x float4; unconditional log,
// mask-multiply; wave + block reduce; 2 atomics per block.
// ---------------------------------------------------------------------------
__global__ __launch_bounds__(256) void bce_kernel(
        const float4* __restrict__ pred4, const float4* __restrict__ tgt4,
        const uint64_t* __restrict__ gt_bin, const uint64_t* __restrict__ pr_bin,
        const uint64_t* __restrict__ gt_sk, const uint64_t* __restrict__ pr_sk,
        float* __restrict__ sums, int* __restrict__ cnts) {
    int tg = blockIdx.x * 256 + threadIdx.x;     // 8 px per thread
    int w = tg >> 3;                             // word index (8 threads share)
    uint64_t sel = (gt_sk[w] & ~pr_bin[w]) | (pr_sk[w] & ~gt_bin[w]);
    uint32_t bits = (uint32_t)(sel >> ((tg & 7) * 8)) & 0xffu;
    float4 pa = pred4[2 * tg], pb = pred4[2 * tg + 1];
    float4 ta = tgt4[2 * tg], tb = tgt4[2 * tg + 1];
    float p[8] = {pa.x, pa.y, pa.z, pa.w, pb.x, pb.y, pb.z, pb.w};
    float t[8] = {ta.x, ta.y, ta.z, ta.w, tb.x, tb.y, tb.z, tb.w};
    float lsum = 0.0f;
    int lcnt = 0;
#pragma unroll
    for (int j = 0; j < 8; ++j) {
        float lp = fmaxf(logf(p[j]), -100.0f);
        float l1 = fmaxf(log1pf(-p[j]), -100.0f);
        float b = -(t[j] * lp + (1.0f - t[j]) * l1);
        uint32_t m = (bits >> j) & 1u;
        lsum = fmaf((float)m, b, lsum);
        lcnt += (int)m;
    }
#pragma unroll
    for (int off = 32; off > 0; off >>= 1) {
        lsum += __shfl_down(lsum, off, 64);
        lcnt += __shfl_down(lcnt, off, 64);
    }
    __shared__ float sred[4];
    __shared__ int cred[4];
    int wave = threadIdx.x >> 6, lane = threadIdx.x & 63;
    if (lane == 0) { sred[wave] = lsum; cred[wave] = lcnt; }
    __syncthreads();
    if (threadIdx.x == 0) {
        float s = sred[0] + sred[1] + sred[2] + sred[3];
        int c = cred[0] + cred[1] + cred[2] + cred[3];
        int img = blockIdx.x >> 7;   // 128 blocks per image (2048 px/block)
        atomicAdd(&sums[img], s);
        atomicAdd(&cnts[img], c);
    }
}

__global__ void final_kernel(const float* __restrict__ sums,
                             const int* __restrict__ cnts,
                             float* __restrict__ out) {
    if (threadIdx.x == 0) {
        float tot = 0.0f;
#pragma unroll
        for (int i = 0; i < NIMG; ++i) {
            float c = (float)cnts[i];
            tot += (c > 0.0f) ? (sums[i] / c) : 0.0f;
        }
        out[0] = tot * (1.0f / NIMG);
    }
}

// ---------------------------------------------------------------------------
extern "C" void kernel_launch(void* const* d_in, const int* in_sizes, int n_in,
                              void* d_out, int out_size, void* d_ws, size_t ws_size,
                              hipStream_t stream) {
    const float* pred = (const float*)d_in[0];
    const float* target = (const float*)d_in[1];
    uint64_t* ws = (uint64_t*)d_ws;
    uint64_t* gt_bin = ws;                      // [0, 32768)
    uint64_t* pr_bin = ws + MASK_WORDS;         // [32768, 65536)
    uint64_t* gt_sk  = ws + 2 * MASK_WORDS;
    uint64_t* pr_sk  = ws + 3 * MASK_WORDS;
    float* sums = (float*)(ws + 4 * MASK_WORDS);
    int* cnts   = (int*)(sums + NIMG);

    pack_kernel<<<TOTAL_PIX / 256, 256, 0, stream>>>(pred, target, gt_bin, pr_bin, sums, cnts);
    // bin region (gt then pr) is 16 contiguous images; same for sk region.
    skel_kernel<<<16, 512, 0, stream>>>(gt_bin, gt_sk);
    bce_kernel<<<TOTAL_PIX / 2048, 256, 0, stream>>>((const float4*)pred, (const float4*)target,
                                                     gt_bin, pr_bin, gt_sk, pr_sk, sums, cnts);
    final_kernel<<<1, 64, 0, stream>>>(sums, cnts, (float*)d_out);
}